// Round 8
// baseline (333.446 us; speedup 1.0000x reference)
//
#include <hip/hip_runtime.h>

// B=16384, DIM=64, 8 coupling steps, H=8, D2=32.
// y = J^{-1} g applied analytically (triangular coupling blocks -> MLP JVPs);
// intermediate states recovered by inverting the flow from z = phi(x).
//
// R8: R7's 16-lane mapping (r = lane&7 owns dims 4r..4r+3 and computes full
// row r of every layer; hb = lane bit3 selects t/s net; all exchanges DPP)
// PLUS: (a) 2 elements per lane — every weight/bias load and its address
// serves two elements, and each dep chain has an independent twin (ILP 2x);
// (b) flow loops fully unrolled with hb folded into base pointers so every
// ds_read is [base + immediate] (no per-net address math); (c) forward
// caches h1/h2 per net (scalars), backward skips eval L1/L2 + tanh and
// recomputes t/s only via L3 from cached h2.

namespace {

typedef _Float16 f16;
typedef f16 f16x2 __attribute__((ext_vector_type(2)));

constexpr int NB = 16384;

constexpr int DPP_X1 = 0xB1;  // quad_perm xor1
constexpr int DPP_X2 = 0x4E;  // quad_perm xor2
constexpr int DPP_X3 = 0x1B;  // quad_perm xor3
constexpr int DPP_R4 = 0x124; // row_ror:4
constexpr int DPP_R8 = 0x128; // row_ror:8 (xor8 in 16-lane group)
constexpr int DPP_HM = 0x141; // row_half_mirror (xor7 in 8)

__device__ __forceinline__ float frcp(float x) { return __builtin_amdgcn_rcpf(x); }

__device__ __forceinline__ float ftanh(float x) {
  float e = __expf(2.f * x);
  return 1.f - 2.f * frcp(e + 1.f);
}

__device__ __forceinline__ float fdot2(f16x2 a, f16x2 b, float c) {
  return __builtin_amdgcn_fdot2(a, b, c, false);
}
__device__ __forceinline__ f16x2 pk(float a, float b) {
  auto r = __builtin_amdgcn_cvt_pkrtz(a, b);
  return __builtin_bit_cast(f16x2, r);
}
template <int C>
__device__ __forceinline__ f16x2 dpph(f16x2 v) {
  int x = __builtin_bit_cast(int, v);
  int r = __builtin_amdgcn_update_dpp(x, x, C, 0xF, 0xF, true);
  return __builtin_bit_cast(f16x2, r);
}
template <int C>
__device__ __forceinline__ float dppf(float v) {
  int x = __float_as_int(v);
  return __int_as_float(__builtin_amdgcn_update_dpp(x, x, C, 0xF, 0xF, true));
}

// Gather the full 32-dim vector as pairs, j-order: Vp[j] = chunk (r^j).
__device__ __forceinline__ void gather_v(const float v4[4], f16x2 Vp[8][2]) {
  Vp[0][0] = pk(v4[0], v4[1]);
  Vp[0][1] = pk(v4[2], v4[3]);
  Vp[4][0] = dpph<DPP_R4>(Vp[0][0]);
  Vp[4][1] = dpph<DPP_R4>(Vp[0][1]);
  Vp[1][0] = dpph<DPP_X1>(Vp[0][0]);
  Vp[1][1] = dpph<DPP_X1>(Vp[0][1]);
  Vp[2][0] = dpph<DPP_X2>(Vp[0][0]);
  Vp[2][1] = dpph<DPP_X2>(Vp[0][1]);
  Vp[3][0] = dpph<DPP_X3>(Vp[0][0]);
  Vp[3][1] = dpph<DPP_X3>(Vp[0][1]);
  Vp[5][0] = dpph<DPP_X1>(Vp[4][0]);
  Vp[5][1] = dpph<DPP_X1>(Vp[4][1]);
  Vp[6][0] = dpph<DPP_X2>(Vp[4][0]);
  Vp[6][1] = dpph<DPP_X2>(Vp[4][1]);
  Vp[7][0] = dpph<DPP_X3>(Vp[4][0]);
  Vp[7][1] = dpph<DPP_X3>(Vp[4][1]);
}

// P[0]=(h[r],h[r^1]) P[1]=(h[r^2],h[r^3]) P[2]=(h[r^7],h[r^6]) P[3]=(h[r^5],h[r^4])
__device__ __forceinline__ void gather_h(float h, f16x2 P[4]) {
  float hx = dppf<DPP_X1>(h);
  P[0] = pk(h, hx);
  P[1] = dpph<DPP_X2>(P[0]);
  P[2] = dpph<DPP_HM>(P[0]);
  P[3] = dpph<DPP_HM>(P[1]);
}

// Forward eval of net (mi+hb) for two elements; caches h1/h2.
__device__ __forceinline__ void net_fwd2(
    const f16x2* __restrict__ pW0, const f16x2* __restrict__ pW1,
    const f16x2* __restrict__ pW2, const f16x2* __restrict__ pB01,
    const f16x2* __restrict__ pB2, int mi, const float vA[4],
    const float vB[4], float oA[4], float oB[4], float& h1cA, float& h1cB,
    float& h2cA, float& h2cB) {
  f16x2 VA[8][2], VB[8][2];
  gather_v(vA, VA);
  gather_v(vB, VB);
  const f16x2 bx = pB01[mi * 8];
  const float b0 = (float)bx[0];
  float sA = b0, sB = b0;
#pragma unroll
  for (int t = 0; t < 4; ++t) {
    float4 w = *(const float4*)(pW0 + mi * 128 + t * 32);
    f16x2 w0 = __builtin_bit_cast(f16x2, w.x);
    f16x2 w1 = __builtin_bit_cast(f16x2, w.y);
    f16x2 w2 = __builtin_bit_cast(f16x2, w.z);
    f16x2 w3 = __builtin_bit_cast(f16x2, w.w);
    sA = fdot2(w0, VA[2 * t][0], sA);
    sA = fdot2(w1, VA[2 * t][1], sA);
    sA = fdot2(w2, VA[2 * t + 1][0], sA);
    sA = fdot2(w3, VA[2 * t + 1][1], sA);
    sB = fdot2(w0, VB[2 * t][0], sB);
    sB = fdot2(w1, VB[2 * t][1], sB);
    sB = fdot2(w2, VB[2 * t + 1][0], sB);
    sB = fdot2(w3, VB[2 * t + 1][1], sB);
  }
  const float h1A = ftanh(sA), h1B = ftanh(sB);
  h1cA = h1A;
  h1cB = h1B;
  f16x2 H1A[4], H1B[4];
  gather_h(h1A, H1A);
  gather_h(h1B, H1B);
  float4 wv = *(const float4*)(pW1 + mi * 32);
  f16x2 a0 = __builtin_bit_cast(f16x2, wv.x);
  f16x2 a1 = __builtin_bit_cast(f16x2, wv.y);
  f16x2 a2 = __builtin_bit_cast(f16x2, wv.z);
  f16x2 a3 = __builtin_bit_cast(f16x2, wv.w);
  const float b1 = (float)bx[1];
  float s2A = b1, s2B = b1;
  s2A = fdot2(a0, H1A[0], s2A);
  s2A = fdot2(a1, H1A[1], s2A);
  s2A = fdot2(a2, H1A[2], s2A);
  s2A = fdot2(a3, H1A[3], s2A);
  s2B = fdot2(a0, H1B[0], s2B);
  s2B = fdot2(a1, H1B[1], s2B);
  s2B = fdot2(a2, H1B[2], s2B);
  s2B = fdot2(a3, H1B[3], s2B);
  const float h2A = ftanh(s2A), h2B = ftanh(s2B);
  h2cA = h2A;
  h2cB = h2B;
  f16x2 H2A[4], H2B[4];
  gather_h(h2A, H2A);
  gather_h(h2B, H2B);
  const float2 b2v = *(const float2*)(pB2 + mi * 16);
  const f16x2 bb0 = __builtin_bit_cast(f16x2, b2v.x);
  const f16x2 bb1 = __builtin_bit_cast(f16x2, b2v.y);
  const float bias3[4] = {(float)bb0[0], (float)bb0[1], (float)bb1[0],
                          (float)bb1[1]};
#pragma unroll
  for (int c = 0; c < 4; ++c) {
    float4 w = *(const float4*)(pW2 + mi * 128 + c * 32);
    f16x2 c0 = __builtin_bit_cast(f16x2, w.x);
    f16x2 c1 = __builtin_bit_cast(f16x2, w.y);
    f16x2 c2 = __builtin_bit_cast(f16x2, w.z);
    f16x2 c3 = __builtin_bit_cast(f16x2, w.w);
    float oa = fdot2(c0, H2A[0], bias3[c]);
    oa = fdot2(c1, H2A[1], oa);
    oa = fdot2(c2, H2A[2], oa);
    oa = fdot2(c3, H2A[3], oa);
    oA[c] = oa;
    float ob = fdot2(c0, H2B[0], bias3[c]);
    ob = fdot2(c1, H2B[1], ob);
    ob = fdot2(c2, H2B[2], ob);
    ob = fdot2(c3, H2B[3], ob);
    oB[c] = ob;
  }
}

// Backward: recompute t/s via L3 from cached h2, JVP at u; two elements.
__device__ __forceinline__ void net_bwd2(
    const f16x2* __restrict__ pW0, const f16x2* __restrict__ pW1,
    const f16x2* __restrict__ pW2, const f16x2* __restrict__ pB2, int mi,
    const float uA[4], const float uB[4], float h1A, float h1B, float h2A,
    float h2B, float oA[4], float oB[4], float jA[4], float jB[4]) {
  f16x2 UA[8][2], UB[8][2];
  gather_v(uA, UA);
  gather_v(uB, UB);
  float suA = 0.f, suB = 0.f;
#pragma unroll
  for (int t = 0; t < 4; ++t) {
    float4 w = *(const float4*)(pW0 + mi * 128 + t * 32);
    f16x2 w0 = __builtin_bit_cast(f16x2, w.x);
    f16x2 w1 = __builtin_bit_cast(f16x2, w.y);
    f16x2 w2 = __builtin_bit_cast(f16x2, w.z);
    f16x2 w3 = __builtin_bit_cast(f16x2, w.w);
    suA = fdot2(w0, UA[2 * t][0], suA);
    suA = fdot2(w1, UA[2 * t][1], suA);
    suA = fdot2(w2, UA[2 * t + 1][0], suA);
    suA = fdot2(w3, UA[2 * t + 1][1], suA);
    suB = fdot2(w0, UB[2 * t][0], suB);
    suB = fdot2(w1, UB[2 * t][1], suB);
    suB = fdot2(w2, UB[2 * t + 1][0], suB);
    suB = fdot2(w3, UB[2 * t + 1][1], suB);
  }
  const float g1A = (1.f - h1A * h1A) * suA;
  const float g1B = (1.f - h1B * h1B) * suB;
  f16x2 G1A[4], G1B[4];
  gather_h(g1A, G1A);
  gather_h(g1B, G1B);
  float4 wv = *(const float4*)(pW1 + mi * 32);
  f16x2 a0 = __builtin_bit_cast(f16x2, wv.x);
  f16x2 a1 = __builtin_bit_cast(f16x2, wv.y);
  f16x2 a2 = __builtin_bit_cast(f16x2, wv.z);
  f16x2 a3 = __builtin_bit_cast(f16x2, wv.w);
  float t2A = fdot2(a0, G1A[0], 0.f);
  t2A = fdot2(a1, G1A[1], t2A);
  t2A = fdot2(a2, G1A[2], t2A);
  t2A = fdot2(a3, G1A[3], t2A);
  float t2B = fdot2(a0, G1B[0], 0.f);
  t2B = fdot2(a1, G1B[1], t2B);
  t2B = fdot2(a2, G1B[2], t2B);
  t2B = fdot2(a3, G1B[3], t2B);
  const float g2A = (1.f - h2A * h2A) * t2A;
  const float g2B = (1.f - h2B * h2B) * t2B;
  f16x2 G2A[4], G2B[4], H2A[4], H2B[4];
  gather_h(g2A, G2A);
  gather_h(g2B, G2B);
  gather_h(h2A, H2A);
  gather_h(h2B, H2B);
  const float2 b2v = *(const float2*)(pB2 + mi * 16);
  const f16x2 bb0 = __builtin_bit_cast(f16x2, b2v.x);
  const f16x2 bb1 = __builtin_bit_cast(f16x2, b2v.y);
  const float bias3[4] = {(float)bb0[0], (float)bb0[1], (float)bb1[0],
                          (float)bb1[1]};
#pragma unroll
  for (int c = 0; c < 4; ++c) {
    float4 w = *(const float4*)(pW2 + mi * 128 + c * 32);
    f16x2 c0 = __builtin_bit_cast(f16x2, w.x);
    f16x2 c1 = __builtin_bit_cast(f16x2, w.y);
    f16x2 c2 = __builtin_bit_cast(f16x2, w.z);
    f16x2 c3 = __builtin_bit_cast(f16x2, w.w);
    float oa = fdot2(c0, H2A[0], bias3[c]);
    oa = fdot2(c1, H2A[1], oa);
    oa = fdot2(c2, H2A[2], oa);
    oa = fdot2(c3, H2A[3], oa);
    oA[c] = oa;
    float ja = fdot2(c0, G2A[0], 0.f);
    ja = fdot2(c1, G2A[1], ja);
    ja = fdot2(c2, G2A[2], ja);
    ja = fdot2(c3, G2A[3], ja);
    jA[c] = ja;
    float ob = fdot2(c0, H2B[0], bias3[c]);
    ob = fdot2(c1, H2B[1], ob);
    ob = fdot2(c2, H2B[2], ob);
    ob = fdot2(c3, H2B[3], ob);
    oB[c] = ob;
    float jb = fdot2(c0, G2B[0], 0.f);
    jb = fdot2(c1, G2B[1], jb);
    jb = fdot2(c2, G2B[2], jb);
    jb = fdot2(c3, G2B[3], jb);
    jB[c] = jb;
  }
}

}  // namespace

// 256 threads = 32 elements/block (2 per lane), grid 512 -> 2048 waves
// (8/CU, 2/SIMD). LDS 39936 B. VGPR capped at 256 by launch_bounds(256,2).
__global__ __launch_bounds__(256, 2) void nf_policy_kernel(
    const float* __restrict__ x, const float* __restrict__ xs,
    const float* __restrict__ gW0, const float* __restrict__ gb0,
    const float* __restrict__ gW1, const float* __restrict__ gb1,
    const float* __restrict__ gW2, const float* __restrict__ gb2,
    float* __restrict__ out) {
  __shared__ __align__(16) f16x2 sXW0[4096];  // [32m][4t][8r][4p]
  __shared__ __align__(16) f16x2 sXW1[1024];  // [32m][8r][4j2]
  __shared__ __align__(16) f16x2 sXW2[4096];  // [32m][4c][8r][4j2]
  __shared__ __align__(16) f16x2 sBx01[256];  // [32m][8r] (b0,b1)
  __shared__ __align__(16) f16x2 sBx2[512];   // [32m][8r][2u]

  const int tid = threadIdx.x;
  const int X0[4] = {0, 2, 7, 5};
  const int X1[4] = {1, 3, 6, 4};
  // ---- stage weights (fp32 global -> xor-ordered f16x2 LDS) ----
  for (int i = tid; i < 4096; i += 256) {  // XW0
    const int p = i & 3, r = (i >> 2) & 7, t = (i >> 5) & 3, m = i >> 7;
    const int g = t * 4 + p, j = g >> 1, hp = g & 1;
    const float* b = gW0 + m * 256 + r * 32 + ((r ^ j) << 2) + hp * 2;
    sXW0[i] = pk(b[0], b[1]);
  }
  for (int i = tid; i < 1024; i += 256) {  // XW1
    const int j2 = i & 3, r = (i >> 2) & 7, m = i >> 5;
    const float* b = gW1 + m * 64 + r * 8;
    sXW1[i] = pk(b[r ^ X0[j2]], b[r ^ X1[j2]]);
  }
  for (int i = tid; i < 4096; i += 256) {  // XW2
    const int j2 = i & 3, r = (i >> 2) & 7, c = (i >> 5) & 3, m = i >> 7;
    const float* b = gW2 + m * 256 + (r * 4 + c) * 8;
    sXW2[i] = pk(b[r ^ X0[j2]], b[r ^ X1[j2]]);
  }
  for (int i = tid; i < 256; i += 256) {  // Bx01
    const int r = i & 7, m = i >> 3;
    sBx01[i] = pk(gb0[m * 8 + r], gb1[m * 8 + r]);
  }
  for (int i = tid; i < 512; i += 256) {  // Bx2
    const int u = i & 1, r = (i >> 1) & 7, m = i >> 4;
    const float* b = gb2 + m * 32 + r * 4 + 2 * u;
    sBx2[i] = pk(b[0], b[1]);
  }
  __syncthreads();

  const int g = tid >> 4;
  const int L = tid & 15;
  const int r = L & 7;
  const int hb = (L >> 3) & 1;  // 0: t-net, 1: s-net
  const int eA = blockIdx.x * 32 + g * 2;
  const int eB = eA + 1;

  // per-lane base pointers (hb and r folded in; all later offsets immediate)
  const f16x2* pW0 = sXW0 + hb * 128 + r * 4;
  const f16x2* pW1 = sXW1 + hb * 32 + r * 4;
  const f16x2* pW2 = sXW2 + hb * 128 + r * 4;
  const f16x2* pB01 = sBx01 + hb * 8 + r;
  const f16x2* pB2 = sBx2 + hb * 16 + r * 2;

  float loA[4], upA[4], avA[4], bvA[4];
  float loB[4], upB[4], avB[4], bvB[4];
  {
    const float4 xl = *(const float4*)(x + (size_t)eA * 64 + r * 4);
    const float4 xu = *(const float4*)(x + (size_t)eA * 64 + 32 + r * 4);
    const float4 sl = *(const float4*)(xs + (size_t)eA * 64 + r * 4);
    const float4 su = *(const float4*)(xs + (size_t)eA * 64 + 32 + r * 4);
    loA[0] = xl.x; loA[1] = xl.y; loA[2] = xl.z; loA[3] = xl.w;
    upA[0] = xu.x; upA[1] = xu.y; upA[2] = xu.z; upA[3] = xu.w;
    avA[0] = -2.f * (xl.x - sl.x); avA[1] = -2.f * (xl.y - sl.y);
    avA[2] = -2.f * (xl.z - sl.z); avA[3] = -2.f * (xl.w - sl.w);
    bvA[0] = -2.f * (xu.x - su.x); bvA[1] = -2.f * (xu.y - su.y);
    bvA[2] = -2.f * (xu.z - su.z); bvA[3] = -2.f * (xu.w - su.w);
  }
  {
    const float4 xl = *(const float4*)(x + (size_t)eB * 64 + r * 4);
    const float4 xu = *(const float4*)(x + (size_t)eB * 64 + 32 + r * 4);
    const float4 sl = *(const float4*)(xs + (size_t)eB * 64 + r * 4);
    const float4 su = *(const float4*)(xs + (size_t)eB * 64 + 32 + r * 4);
    loB[0] = xl.x; loB[1] = xl.y; loB[2] = xl.z; loB[3] = xl.w;
    upB[0] = xu.x; upB[1] = xu.y; upB[2] = xu.z; upB[3] = xu.w;
    avB[0] = -2.f * (xl.x - sl.x); avB[1] = -2.f * (xl.y - sl.y);
    avB[2] = -2.f * (xl.z - sl.z); avB[3] = -2.f * (xl.w - sl.w);
    bvB[0] = -2.f * (xu.x - su.x); bvB[1] = -2.f * (xu.y - su.y);
    bvB[2] = -2.f * (xu.z - su.z); bvB[3] = -2.f * (xu.w - su.w);
  }

  float h1cA[16], h1cB[16], h2cA[16], h2cB[16];
  float oA[4], oB[4], jA[4], jB[4];

  // ---------------- forward: z = phi(x); cache h1/h2 ----------------
#pragma unroll
  for (int i = 0; i < 8; ++i) {
    net_fwd2(pW0, pW1, pW2, pB01, pB2, i * 4, loA, loB, oA, oB,
             h1cA[2 * i], h1cB[2 * i], h2cA[2 * i], h2cB[2 * i]);
#pragma unroll
    for (int c = 0; c < 4; ++c) {
      const float oxA = dppf<DPP_R8>(oA[c]);
      const float oxB = dppf<DPP_R8>(oB[c]);
      const float ttA = hb ? oxA : oA[c], ssA = hb ? oA[c] : oxA;
      const float ttB = hb ? oxB : oB[c], ssB = hb ? oB[c] : oxB;
      upA[c] = fmaf(upA[c], __expf(ssA), ttA);
      upB[c] = fmaf(upB[c], __expf(ssB), ttB);
    }
    net_fwd2(pW0, pW1, pW2, pB01, pB2, i * 4 + 2, upA, upB, oA, oB,
             h1cA[2 * i + 1], h1cB[2 * i + 1], h2cA[2 * i + 1],
             h2cB[2 * i + 1]);
#pragma unroll
    for (int c = 0; c < 4; ++c) {
      const float oxA = dppf<DPP_R8>(oA[c]);
      const float oxB = dppf<DPP_R8>(oB[c]);
      const float ttA = hb ? oxA : oA[c], ssA = hb ? oA[c] : oxA;
      const float ttB = hb ? oxB : oB[c], ssB = hb ? oB[c] : oxB;
      loA[c] = fmaf(loA[c], __expf(ssA), ttA);
      loB[c] = fmaf(loB[c], __expf(ssB), ttB);
    }
  }

  // ------------- backward: y = J^{-1} g, inverting the flow -------------
#pragma unroll
  for (int ii = 0; ii < 8; ++ii) {
    const int i = 7 - ii;
    // T2^{-1}: t2/s2 at up' (cached), JVP at bv
    net_bwd2(pW0, pW1, pW2, pB2, i * 4 + 2, bvA, bvB, h1cA[2 * i + 1],
             h1cB[2 * i + 1], h2cA[2 * i + 1], h2cB[2 * i + 1], oA, oB, jA,
             jB);
#pragma unroll
    for (int c = 0; c < 4; ++c) {
      const float oxA = dppf<DPP_R8>(oA[c]);
      const float jxA = dppf<DPP_R8>(jA[c]);
      const float ttA = hb ? oxA : oA[c], ssA = hb ? oA[c] : oxA;
      const float utA = hb ? jxA : jA[c], usA = hb ? jA[c] : jxA;
      const float esiA = __expf(-ssA);
      const float dA = loA[c] - ttA;
      loA[c] = dA * esiA;
      avA[c] = (avA[c] - utA - dA * usA) * esiA;
      const float oxB = dppf<DPP_R8>(oB[c]);
      const float jxB = dppf<DPP_R8>(jB[c]);
      const float ttB = hb ? oxB : oB[c], ssB = hb ? oB[c] : oxB;
      const float utB = hb ? jxB : jB[c], usB = hb ? jB[c] : jxB;
      const float esiB = __expf(-ssB);
      const float dB = loB[c] - ttB;
      loB[c] = dB * esiB;
      avB[c] = (avB[c] - utB - dB * usB) * esiB;
    }
    // T1^{-1}: t1/s1 at lo (cached), JVP at av (updated)
    net_bwd2(pW0, pW1, pW2, pB2, i * 4, avA, avB, h1cA[2 * i], h1cB[2 * i],
             h2cA[2 * i], h2cB[2 * i], oA, oB, jA, jB);
#pragma unroll
    for (int c = 0; c < 4; ++c) {
      const float oxA = dppf<DPP_R8>(oA[c]);
      const float jxA = dppf<DPP_R8>(jA[c]);
      const float ttA = hb ? oxA : oA[c], ssA = hb ? oA[c] : oxA;
      const float utA = hb ? jxA : jA[c], usA = hb ? jA[c] : jxA;
      const float esiA = __expf(-ssA);
      const float dA = upA[c] - ttA;
      upA[c] = dA * esiA;
      bvA[c] = (bvA[c] - utA - dA * usA) * esiA;
      const float oxB = dppf<DPP_R8>(oB[c]);
      const float jxB = dppf<DPP_R8>(jB[c]);
      const float ttB = hb ? oxB : oB[c], ssB = hb ? oB[c] : oxB;
      const float utB = hb ? jxB : jB[c], usB = hb ? jB[c] : jxB;
      const float esiB = __expf(-ssB);
      const float dB = upB[c] - ttB;
      upB[c] = dB * esiB;
      bvB[c] = (bvB[c] - utB - dB * usB) * esiB;
    }
  }

  if (!hb) {
    float4 v;
    v.x = avA[0]; v.y = avA[1]; v.z = avA[2]; v.w = avA[3];
    *(float4*)(out + (size_t)eA * 64 + r * 4) = v;
    v.x = bvA[0]; v.y = bvA[1]; v.z = bvA[2]; v.w = bvA[3];
    *(float4*)(out + (size_t)eA * 64 + 32 + r * 4) = v;
    v.x = avB[0]; v.y = avB[1]; v.z = avB[2]; v.w = avB[3];
    *(float4*)(out + (size_t)eB * 64 + r * 4) = v;
    v.x = bvB[0]; v.y = bvB[1]; v.z = bvB[2]; v.w = bvB[3];
    *(float4*)(out + (size_t)eB * 64 + 32 + r * 4) = v;
  }
}

extern "C" void kernel_launch(void* const* d_in, const int* in_sizes, int n_in,
                              void* d_out, int out_size, void* d_ws,
                              size_t ws_size, hipStream_t stream) {
  const float* x  = (const float*)d_in[0];
  const float* xs = (const float*)d_in[1];
  const float* W0 = (const float*)d_in[2];
  const float* b0 = (const float*)d_in[3];
  const float* W1 = (const float*)d_in[4];
  const float* b1 = (const float*)d_in[5];
  const float* W2 = (const float*)d_in[6];
  const float* b2 = (const float*)d_in[7];
  float* out = (float*)d_out;

  dim3 grid(NB / 32);  // 512 blocks, 32 elements each (2 per lane)
  dim3 block(256);
  nf_policy_kernel<<<grid, block, 0, stream>>>(x, xs, W0, b0, W1, b1, W2, b2,
                                               out);
}

// Round 9
// 95.446 us; speedup vs baseline: 3.4936x; 3.4936x over previous
//
#include <hip/hip_runtime.h>

// B=16384, DIM=64, 8 coupling steps, H=8, D2=32.
// y = J^{-1} g applied analytically (triangular coupling blocks -> MLP JVPs);
// intermediate states recovered by inverting the flow from z = phi(x).
//
// R9: MFMA formulation. One wave = 16 elements (n = lane&15); lane quad
// q = lane>>4 owns state dims {8q..8q+7}. Per half-step, BOTH nets (t,s)
// are evaluated by one MFMA chain with t rows 0-7 / s rows 8-15 stacked in M:
//   L1: mfma_f32_16x16x32_f16  A=[W0t;W0s](16x32)  B=V(32x16)
//   L2: mfma_f32_16x16x16f16   A=blockdiag(W1t,W1s) B=H1
//   L3: 4x mfma_f32_16x16x16f16, W2 rows pre-permuted so D rows land
//       exactly in the state layout (lane q gets dims 8q..8q+7).
// Key layout identity (gfx950, verified m89): D (col=lane&15,row=4q+reg)
// == B-operand (n=lane&15, k=4q+j) for K=16 -> tanh(D)->pack is per-lane,
// ZERO cross-lane ops anywhere in the flow. JVP shares all A-fragments.
// Weights staged once to LDS (~43 KiB) as f16 in MFMA A-fragment order.

namespace {

typedef __fp16 f16x2 __attribute__((ext_vector_type(2)));
typedef __fp16 v4h __attribute__((ext_vector_type(4)));
typedef __fp16 v8h __attribute__((ext_vector_type(8)));
typedef float f32x4 __attribute__((ext_vector_type(4)));

constexpr int NB = 16384;

__device__ __forceinline__ float frcp(float x) { return __builtin_amdgcn_rcpf(x); }
__device__ __forceinline__ float ftanh(float x) {
  float e = __expf(2.f * x);
  return 1.f - 2.f * frcp(e + 1.f);
}
__device__ __forceinline__ f16x2 pk(float a, float b) {
  return __builtin_amdgcn_cvt_pkrtz(a, b);
}

union U8 { v8h v; f16x2 h[4]; };
union U4 { v4h v; f16x2 h[2]; };

// net pair p (0..15): step i = p>>1, half = p&1 -> t-net base m0.
__device__ __forceinline__ int pbase(int p) {
  return ((p >> 1) << 2) + ((p & 1) << 1);
}

// Evaluate both nets of pair p at v (and JVP at u): t/s (+ut/us) per lane,
// local j=0..7 <-> state dims 8q+j.
template <bool JVP>
__device__ __forceinline__ void pair_apply(
    const f16x2* __restrict__ LW0, const f16x2* __restrict__ LW1,
    const f16x2* __restrict__ LW2, const float* __restrict__ LB0,
    const float* __restrict__ LB1, const float* __restrict__ LB2, int p,
    int n, int q, const float v[8], const float* __restrict__ u, float t8[8],
    float s8[8], float* __restrict__ ut8, float* __restrict__ us8) {
  v4h z4;
#pragma unroll
  for (int jj = 0; jj < 4; ++jj) z4[jj] = (__fp16)0.f;
  const f32x4 zc = {0.f, 0.f, 0.f, 0.f};

  U8 B;
  B.h[0] = pk(v[0], v[1]);
  B.h[1] = pk(v[2], v[3]);
  B.h[2] = pk(v[4], v[5]);
  B.h[3] = pk(v[6], v[7]);

  const v8h A0 = *(const v8h*)(LW0 + ((p * 64 + q * 16 + n) << 2));
  const f32x4 c0 = *(const f32x4*)(LB0 + p * 16 + q * 4);
  f32x4 d1 = __builtin_amdgcn_mfma_f32_16x16x32_f16(A0, B.v, c0, 0, 0, 0);
  float h1[4];
#pragma unroll
  for (int r = 0; r < 4; ++r) h1[r] = ftanh(d1[r]);
  U4 H1;
  H1.h[0] = pk(h1[0], h1[1]);
  H1.h[1] = pk(h1[2], h1[3]);

  const bool act1 = (n < 8) == (q < 2);
  v4h A1 = *(const v4h*)(LW1 + (p * 64 + ((n & 7) << 2) + ((q & 1) << 1) +
                                ((n >= 8) ? 32 : 0)));
  A1 = act1 ? A1 : z4;
  const f32x4 c1 = *(const f32x4*)(LB1 + p * 16 + q * 4);
  f32x4 d2 = __builtin_amdgcn_mfma_f32_16x16x16f16(A1, H1.v, c1, 0, 0, 0);
  float h2[4];
#pragma unroll
  for (int r = 0; r < 4; ++r) h2[r] = ftanh(d2[r]);
  U4 H2;
  H2.h[0] = pk(h2[0], h2[1]);
  H2.h[1] = pk(h2[2], h2[3]);

  U4 G2;
  if constexpr (JVP) {
    U8 Bu;
    Bu.h[0] = pk(u[0], u[1]);
    Bu.h[1] = pk(u[2], u[3]);
    Bu.h[2] = pk(u[4], u[5]);
    Bu.h[3] = pk(u[6], u[7]);
    f32x4 d1u = __builtin_amdgcn_mfma_f32_16x16x32_f16(A0, Bu.v, zc, 0, 0, 0);
    float g1[4];
#pragma unroll
    for (int r = 0; r < 4; ++r) g1[r] = (1.f - h1[r] * h1[r]) * d1u[r];
    U4 G1;
    G1.h[0] = pk(g1[0], g1[1]);
    G1.h[1] = pk(g1[2], g1[3]);
    f32x4 d2u = __builtin_amdgcn_mfma_f32_16x16x16f16(A1, G1.v, zc, 0, 0, 0);
    float g2[4];
#pragma unroll
    for (int r = 0; r < 4; ++r) g2[r] = (1.f - h2[r] * h2[r]) * d2u[r];
    G2.h[0] = pk(g2[0], g2[1]);
    G2.h[1] = pk(g2[2], g2[3]);
  }

  // L3: 4 blocks = {tX, tY, sX, sY}; W2 rows pre-permuted so lane q's D rows
  // 4q+r land at t/s local dims {r} (X) and {4+r} (Y).
#pragma unroll
  for (int b = 0; b < 4; ++b) {
    const bool act = (b < 2) == (q < 2);
    v4h Ab = *(const v4h*)(LW2 + (p * 256 + b * 64 + n * 4 + ((q & 1) << 1)));
    Ab = act ? Ab : z4;
    const f32x4 cb = *(const f32x4*)(LB2 + (p * 4 + b) * 16 + q * 4);
    f32x4 ob = __builtin_amdgcn_mfma_f32_16x16x16f16(Ab, H2.v, cb, 0, 0, 0);
    float* dst = (b < 2) ? t8 : s8;
    const int off = (b & 1) * 4;
#pragma unroll
    for (int r = 0; r < 4; ++r) dst[off + r] = ob[r];
    if constexpr (JVP) {
      f32x4 jb = __builtin_amdgcn_mfma_f32_16x16x16f16(Ab, G2.v, zc, 0, 0, 0);
      float* jdst = (b < 2) ? ut8 : us8;
#pragma unroll
      for (int r = 0; r < 4; ++r) jdst[off + r] = jb[r];
    }
  }
}

}  // namespace

// 256 threads = 4 waves = 64 elements/block, grid 256 -> 1024 waves (1/SIMD).
// LDS ~43 KiB -> 1 block/CU.
__global__ __launch_bounds__(256, 1) void nf_policy_kernel(
    const float* __restrict__ x, const float* __restrict__ xs,
    const float* __restrict__ gW0, const float* __restrict__ gb0,
    const float* __restrict__ gW1, const float* __restrict__ gb1,
    const float* __restrict__ gW2, const float* __restrict__ gb2,
    float* __restrict__ out) {
  __shared__ __align__(16) f16x2 LW0[4096];  // [16p][4q][16m][4w] A-frags L1
  __shared__ __align__(16) f16x2 LW1[1024];  // [16p][2half][8row][4kk]
  __shared__ __align__(16) f16x2 LW2[4096];  // [16p][4b][16m][4kk(2 used)]
  __shared__ __align__(16) float LB0[256];   // [16p][16m]
  __shared__ __align__(16) float LB1[256];   // [16p][16m]
  __shared__ __align__(16) float LB2[1024];  // [16p][4b][16m]

  const int tid = threadIdx.x;
  // ---- stage weights: fp32 global -> f16 LDS in MFMA A-fragment order ----
  for (int i = tid; i < 4096; i += 256) {  // LW0
    const int p = i >> 8, rem = i & 255, q = rem >> 6, rem2 = rem & 63;
    const int mm = rem2 >> 2, w = rem2 & 3;
    const int net = pbase(p) + (mm >> 3);
    const int h = mm & 7, k0 = q * 8 + w * 2;
    const float* src = gW0 + net * 256 + h * 32 + k0;
    LW0[i] = pk(src[0], src[1]);
  }
  for (int i = tid; i < 1024; i += 256) {  // LW1
    const int p = i >> 6, rem = i & 63, half = rem >> 5;
    const int row = (rem >> 2) & 7, kk = rem & 3;
    const int net = pbase(p) + half;
    const float* src = gW1 + net * 64 + row * 8 + kk * 2;
    LW1[i] = pk(src[0], src[1]);
  }
  for (int i = tid; i < 4096; i += 256) {  // LW2 (rows permuted)
    const int p = i >> 8, rem = i & 255, b = rem >> 6, rem2 = rem & 63;
    const int mm = rem2 >> 2, kk = rem2 & 3;
    const int net = pbase(p) + (b >> 1);
    const int d = 8 * (mm >> 2) + ((b & 1) << 2) + (mm & 3);
    const float* src = gW2 + net * 256 + d * 8 + kk * 2;
    LW2[i] = pk(src[0], src[1]);
  }
  for (int i = tid; i < 256; i += 256) {  // LB0/LB1
    const int p = i >> 4, mm = i & 15;
    const int net = pbase(p) + (mm >> 3);
    LB0[i] = gb0[net * 8 + (mm & 7)];
    LB1[i] = gb1[net * 8 + (mm & 7)];
  }
  for (int i = tid; i < 1024; i += 256) {  // LB2 (permuted like LW2 rows)
    const int p = i >> 6, b = (i >> 4) & 3, mm = i & 15;
    const int net = pbase(p) + (b >> 1);
    const int d = 8 * (mm >> 2) + ((b & 1) << 2) + (mm & 3);
    LB2[i] = gb2[net * 32 + d];
  }
  __syncthreads();

  const int lane = tid & 63;
  const int wv = tid >> 6;
  const int n = lane & 15;   // element within wave; MFMA col / A row
  const int q = lane >> 4;   // quad: owns state dims 8q..8q+7
  const int e = blockIdx.x * 64 + wv * 16 + n;

  float lo[8], up[8], av[8], bv[8];
  {
    const float* xe = x + (size_t)e * 64;
    const float* se = xs + (size_t)e * 64;
    const float4 a0 = *(const float4*)(xe + q * 8);
    const float4 a1 = *(const float4*)(xe + q * 8 + 4);
    const float4 u0 = *(const float4*)(xe + 32 + q * 8);
    const float4 u1 = *(const float4*)(xe + 32 + q * 8 + 4);
    const float4 p0 = *(const float4*)(se + q * 8);
    const float4 p1 = *(const float4*)(se + q * 8 + 4);
    const float4 r0 = *(const float4*)(se + 32 + q * 8);
    const float4 r1 = *(const float4*)(se + 32 + q * 8 + 4);
    lo[0] = a0.x; lo[1] = a0.y; lo[2] = a0.z; lo[3] = a0.w;
    lo[4] = a1.x; lo[5] = a1.y; lo[6] = a1.z; lo[7] = a1.w;
    up[0] = u0.x; up[1] = u0.y; up[2] = u0.z; up[3] = u0.w;
    up[4] = u1.x; up[5] = u1.y; up[6] = u1.z; up[7] = u1.w;
    av[0] = -2.f * (a0.x - p0.x); av[1] = -2.f * (a0.y - p0.y);
    av[2] = -2.f * (a0.z - p0.z); av[3] = -2.f * (a0.w - p0.w);
    av[4] = -2.f * (a1.x - p1.x); av[5] = -2.f * (a1.y - p1.y);
    av[6] = -2.f * (a1.z - p1.z); av[7] = -2.f * (a1.w - p1.w);
    bv[0] = -2.f * (u0.x - r0.x); bv[1] = -2.f * (u0.y - r0.y);
    bv[2] = -2.f * (u0.z - r0.z); bv[3] = -2.f * (u0.w - r0.w);
    bv[4] = -2.f * (u1.x - r1.x); bv[5] = -2.f * (u1.y - r1.y);
    bv[6] = -2.f * (u1.z - r1.z); bv[7] = -2.f * (u1.w - r1.w);
  }

  float t8[8], s8[8], ut8[8], us8[8];

  // ---------------- forward: z = phi(x) ----------------
#pragma unroll 1
  for (int i = 0; i < 8; ++i) {
    pair_apply<false>(LW0, LW1, LW2, LB0, LB1, LB2, 2 * i, n, q, lo, nullptr,
                      t8, s8, nullptr, nullptr);
#pragma unroll
    for (int j = 0; j < 8; ++j) up[j] = fmaf(up[j], __expf(s8[j]), t8[j]);
    pair_apply<false>(LW0, LW1, LW2, LB0, LB1, LB2, 2 * i + 1, n, q, up,
                      nullptr, t8, s8, nullptr, nullptr);
#pragma unroll
    for (int j = 0; j < 8; ++j) lo[j] = fmaf(lo[j], __expf(s8[j]), t8[j]);
  }

  // ------------- backward: y = J^{-1} g, inverting the flow -------------
#pragma unroll 1
  for (int i = 7; i >= 0; --i) {
    // T2^{-1}: eval t2/s2 at up', JVP at bv
    pair_apply<true>(LW0, LW1, LW2, LB0, LB1, LB2, 2 * i + 1, n, q, up, bv,
                     t8, s8, ut8, us8);
#pragma unroll
    for (int j = 0; j < 8; ++j) {
      const float esi = __expf(-s8[j]);
      const float d = lo[j] - t8[j];
      lo[j] = d * esi;
      av[j] = (av[j] - ut8[j] - d * us8[j]) * esi;
    }
    // T1^{-1}: eval t1/s1 at lo (pre-step), JVP at av (updated)
    pair_apply<true>(LW0, LW1, LW2, LB0, LB1, LB2, 2 * i, n, q, lo, av, t8,
                     s8, ut8, us8);
#pragma unroll
    for (int j = 0; j < 8; ++j) {
      const float esi = __expf(-s8[j]);
      const float d = up[j] - t8[j];
      up[j] = d * esi;
      bv[j] = (bv[j] - ut8[j] - d * us8[j]) * esi;
    }
  }

  {
    float* oe = out + (size_t)e * 64;
    float4 v;
    v.x = av[0]; v.y = av[1]; v.z = av[2]; v.w = av[3];
    *(float4*)(oe + q * 8) = v;
    v.x = av[4]; v.y = av[5]; v.z = av[6]; v.w = av[7];
    *(float4*)(oe + q * 8 + 4) = v;
    v.x = bv[0]; v.y = bv[1]; v.z = bv[2]; v.w = bv[3];
    *(float4*)(oe + 32 + q * 8) = v;
    v.x = bv[4]; v.y = bv[5]; v.z = bv[6]; v.w = bv[7];
    *(float4*)(oe + 32 + q * 8 + 4) = v;
  }
}

extern "C" void kernel_launch(void* const* d_in, const int* in_sizes, int n_in,
                              void* d_out, int out_size, void* d_ws,
                              size_t ws_size, hipStream_t stream) {
  const float* x  = (const float*)d_in[0];
  const float* xs = (const float*)d_in[1];
  const float* W0 = (const float*)d_in[2];
  const float* b0 = (const float*)d_in[3];
  const float* W1 = (const float*)d_in[4];
  const float* b1 = (const float*)d_in[5];
  const float* W2 = (const float*)d_in[6];
  const float* b2 = (const float*)d_in[7];
  float* out = (float*)d_out;

  dim3 grid(NB / 64);  // 256 blocks, 64 elements each (16 per wave)
  dim3 block(256);
  nf_policy_kernel<<<grid, block, 0, stream>>>(x, xs, W0, b0, W1, b1, W2, b2,
                                               out);
}

// Round 10
// 95.421 us; speedup vs baseline: 3.4945x; 1.0003x over previous
//
#include <hip/hip_runtime.h>

// B=16384, DIM=64, 8 coupling steps, H=8, D2=32.
// y = J^{-1} g applied analytically (triangular coupling blocks -> MLP JVPs);
// intermediate states recovered by inverting the flow from z = phi(x).
//
// R10 = R9 MFMA formulation +
//  (a) FULL unroll of fwd/bwd loops: pair index p compile-time -> all LDS
//      addresses static, loads hoist/pipeline across pairs;
//  (b) forward caches H1/H2 MFMA fragments in LDS (16B/lane/half-step,
//      64 KiB); backward skips the serial L1->tanh->L2->tanh eval chain and
//      recomputes t/s with 4 independent L3 MFMAs from cached H2.
// Layout identity (gfx950, verified m89): D (col=lane&15,row=4q+reg) ==
// B-operand (n=lane&15,k=4q+j) for K=16 -> tanh(D)->pack is per-lane, zero
// cross-lane ops. One wave = 16 elements; 1024 waves = 1/SIMD (hard cap), so
// ILP/pipelining inside the wave is the only latency lever.

namespace {

typedef __fp16 f16x2 __attribute__((ext_vector_type(2)));
typedef __fp16 v4h __attribute__((ext_vector_type(4)));
typedef __fp16 v8h __attribute__((ext_vector_type(8)));
typedef float f32x4 __attribute__((ext_vector_type(4)));

constexpr int NB = 16384;

__device__ __forceinline__ float frcp(float x) { return __builtin_amdgcn_rcpf(x); }
__device__ __forceinline__ float ftanh(float x) {
  float e = __expf(2.f * x);
  return 1.f - 2.f * frcp(e + 1.f);
}
__device__ __forceinline__ f16x2 pk(float a, float b) {
  return __builtin_amdgcn_cvt_pkrtz(a, b);
}

union U8 { v8h v; f16x2 h[4]; float4 f4; };
union U4 { v4h v; f16x2 h[2]; float2 f2; };

// net pair p (0..15): step i = p>>1, half = p&1 -> t-net base.
__device__ __forceinline__ int pbase(int p) {
  return ((p >> 1) << 2) + ((p & 1) << 1);
}

}  // namespace

// 256 threads = 4 waves = 64 elements/block, grid 256 -> 1024 waves (1/SIMD),
// 1 block/CU. LDS: 43 KiB weights + 64 KiB H-cache = 107 KiB.
__global__ __launch_bounds__(256, 1) void nf_policy_kernel(
    const float* __restrict__ x, const float* __restrict__ xs,
    const float* __restrict__ gW0, const float* __restrict__ gb0,
    const float* __restrict__ gW1, const float* __restrict__ gb1,
    const float* __restrict__ gW2, const float* __restrict__ gb2,
    float* __restrict__ out) {
  __shared__ __align__(16) f16x2 LW0[4096];  // [16p][4q][16m][4w] A-frags L1
  __shared__ __align__(16) f16x2 LW1[1024];  // [16p][2half][8row][4kk]
  __shared__ __align__(16) f16x2 LW2[4096];  // [16p][4b][16m][4kk(2 used)]
  __shared__ __align__(16) float LB0[256];   // [16p][16m]
  __shared__ __align__(16) float LB1[256];   // [16p][16m]
  __shared__ __align__(16) float LB2[1024];  // [16p][4b][16m]
  __shared__ __align__(16) float4 sHC[4096]; // [16p][256 tid] H1H2 frag cache

  const int tid = threadIdx.x;
  // ---- stage weights: fp32 global -> f16 LDS in MFMA A-fragment order ----
  for (int i = tid; i < 4096; i += 256) {  // LW0
    const int p = i >> 8, rem = i & 255, qq = rem >> 6, rem2 = rem & 63;
    const int mm = rem2 >> 2, w = rem2 & 3;
    const int net = pbase(p) + (mm >> 3);
    const int h = mm & 7, k0 = qq * 8 + w * 2;
    const float* src = gW0 + net * 256 + h * 32 + k0;
    LW0[i] = pk(src[0], src[1]);
  }
  for (int i = tid; i < 1024; i += 256) {  // LW1
    const int p = i >> 6, rem = i & 63, half = rem >> 5;
    const int row = (rem >> 2) & 7, kk = rem & 3;
    const int net = pbase(p) + half;
    const float* src = gW1 + net * 64 + row * 8 + kk * 2;
    LW1[i] = pk(src[0], src[1]);
  }
  for (int i = tid; i < 4096; i += 256) {  // LW2 (rows permuted)
    const int p = i >> 8, rem = i & 255, b = rem >> 6, rem2 = rem & 63;
    const int mm = rem2 >> 2, kk = rem2 & 3;
    const int net = pbase(p) + (b >> 1);
    const int d = 8 * (mm >> 2) + ((b & 1) << 2) + (mm & 3);
    const float* src = gW2 + net * 256 + d * 8 + kk * 2;
    LW2[i] = pk(src[0], src[1]);
  }
  for (int i = tid; i < 256; i += 256) {  // LB0/LB1
    const int p = i >> 4, mm = i & 15;
    const int net = pbase(p) + (mm >> 3);
    LB0[i] = gb0[net * 8 + (mm & 7)];
    LB1[i] = gb1[net * 8 + (mm & 7)];
  }
  for (int i = tid; i < 1024; i += 256) {  // LB2 (permuted like LW2 rows)
    const int p = i >> 6, b = (i >> 4) & 3, mm = i & 15;
    const int net = pbase(p) + (b >> 1);
    const int d = 8 * (mm >> 2) + ((b & 1) << 2) + (mm & 3);
    LB2[i] = gb2[net * 32 + d];
  }
  __syncthreads();

  const int lane = tid & 63;
  const int wv = tid >> 6;
  const int n = lane & 15;   // element within wave; MFMA col / A row
  const int q = lane >> 4;   // quad: owns state dims 8q..8q+7
  const int e = blockIdx.x * 64 + wv * 16 + n;

  v4h z4;
#pragma unroll
  for (int jj = 0; jj < 4; ++jj) z4[jj] = (__fp16)0.f;
  const f32x4 zc = {0.f, 0.f, 0.f, 0.f};
  const bool act1 = (n < 8) == (q < 2);
  const int a1off = ((n & 7) << 2) + ((q & 1) << 1) + ((n >= 8) ? 32 : 0);
  const int abbase = n * 4 + ((q & 1) << 1);

  float lo[8], up[8], av[8], bv[8];
  {
    const float* xe = x + (size_t)e * 64;
    const float* se = xs + (size_t)e * 64;
    const float4 a0 = *(const float4*)(xe + q * 8);
    const float4 a1 = *(const float4*)(xe + q * 8 + 4);
    const float4 u0 = *(const float4*)(xe + 32 + q * 8);
    const float4 u1 = *(const float4*)(xe + 32 + q * 8 + 4);
    const float4 p0 = *(const float4*)(se + q * 8);
    const float4 p1 = *(const float4*)(se + q * 8 + 4);
    const float4 r0 = *(const float4*)(se + 32 + q * 8);
    const float4 r1 = *(const float4*)(se + 32 + q * 8 + 4);
    lo[0] = a0.x; lo[1] = a0.y; lo[2] = a0.z; lo[3] = a0.w;
    lo[4] = a1.x; lo[5] = a1.y; lo[6] = a1.z; lo[7] = a1.w;
    up[0] = u0.x; up[1] = u0.y; up[2] = u0.z; up[3] = u0.w;
    up[4] = u1.x; up[5] = u1.y; up[6] = u1.z; up[7] = u1.w;
    av[0] = -2.f * (a0.x - p0.x); av[1] = -2.f * (a0.y - p0.y);
    av[2] = -2.f * (a0.z - p0.z); av[3] = -2.f * (a0.w - p0.w);
    av[4] = -2.f * (a1.x - p1.x); av[5] = -2.f * (a1.y - p1.y);
    av[6] = -2.f * (a1.z - p1.z); av[7] = -2.f * (a1.w - p1.w);
    bv[0] = -2.f * (u0.x - r0.x); bv[1] = -2.f * (u0.y - r0.y);
    bv[2] = -2.f * (u0.z - r0.z); bv[3] = -2.f * (u0.w - r0.w);
    bv[4] = -2.f * (u1.x - r1.x); bv[5] = -2.f * (u1.y - r1.y);
    bv[6] = -2.f * (u1.z - r1.z); bv[7] = -2.f * (u1.w - r1.w);
  }

  float t8[8], s8[8], ut8[8], us8[8];

  // ---------------- forward: z = phi(x); cache H1/H2 frags ---------------
#pragma unroll
  for (int hs = 0; hs < 16; ++hs) {
    const int p = hs;
    float* v = (p & 1) ? up : lo;       // input state of this pair
    float* w = (p & 1) ? lo : up;       // state being updated
    U8 B;
    B.h[0] = pk(v[0], v[1]);
    B.h[1] = pk(v[2], v[3]);
    B.h[2] = pk(v[4], v[5]);
    B.h[3] = pk(v[6], v[7]);
    const v8h A0 = *(const v8h*)(LW0 + ((p * 64 + q * 16 + n) << 2));
    const f32x4 c0 = *(const f32x4*)(LB0 + p * 16 + q * 4);
    f32x4 d1 = __builtin_amdgcn_mfma_f32_16x16x32_f16(A0, B.v, c0, 0, 0, 0);
    float h1[4];
#pragma unroll
    for (int r = 0; r < 4; ++r) h1[r] = ftanh(d1[r]);
    U4 H1;
    H1.h[0] = pk(h1[0], h1[1]);
    H1.h[1] = pk(h1[2], h1[3]);
    v4h A1 = *(const v4h*)(LW1 + (p * 64 + a1off));
    A1 = act1 ? A1 : z4;
    const f32x4 c1 = *(const f32x4*)(LB1 + p * 16 + q * 4);
    f32x4 d2 = __builtin_amdgcn_mfma_f32_16x16x16f16(A1, H1.v, c1, 0, 0, 0);
    float h2[4];
#pragma unroll
    for (int r = 0; r < 4; ++r) h2[r] = ftanh(d2[r]);
    U4 H2;
    H2.h[0] = pk(h2[0], h2[1]);
    H2.h[1] = pk(h2[2], h2[3]);
    // cache both fragments (one b128 store)
    {
      float4 pkd;
      pkd.x = __builtin_bit_cast(float, H1.h[0]);
      pkd.y = __builtin_bit_cast(float, H1.h[1]);
      pkd.z = __builtin_bit_cast(float, H2.h[0]);
      pkd.w = __builtin_bit_cast(float, H2.h[1]);
      sHC[p * 256 + tid] = pkd;
    }
#pragma unroll
    for (int b = 0; b < 4; ++b) {
      const bool act = (b < 2) == (q < 2);
      v4h Ab = *(const v4h*)(LW2 + (p * 256 + b * 64 + abbase));
      Ab = act ? Ab : z4;
      const f32x4 cb = *(const f32x4*)(LB2 + (p * 4 + b) * 16 + q * 4);
      f32x4 ob = __builtin_amdgcn_mfma_f32_16x16x16f16(Ab, H2.v, cb, 0, 0, 0);
      float* dst = (b < 2) ? t8 : s8;
      const int off = (b & 1) * 4;
#pragma unroll
      for (int r = 0; r < 4; ++r) dst[off + r] = ob[r];
    }
#pragma unroll
    for (int j = 0; j < 8; ++j) w[j] = fmaf(w[j], __expf(s8[j]), t8[j]);
  }

  // ------------- backward: y = J^{-1} g, inverting the flow -------------
#pragma unroll
  for (int hs = 15; hs >= 0; --hs) {
    const int p = hs;
    float* st = (p & 1) ? lo : up;      // state updated by this pair in fwd
    float* dme = (p & 1) ? av : bv;     // dual of that state
    float* dot = (p & 1) ? bv : av;     // dual of the pair's input state
    // cached fragments
    U4 H1, H2;
    {
      const float4 pkd = sHC[p * 256 + tid];
      H1.h[0] = __builtin_bit_cast(f16x2, pkd.x);
      H1.h[1] = __builtin_bit_cast(f16x2, pkd.y);
      H2.h[0] = __builtin_bit_cast(f16x2, pkd.z);
      H2.h[1] = __builtin_bit_cast(f16x2, pkd.w);
    }
    // JVP at the dual of the input state
    U8 Bu;
    Bu.h[0] = pk(dot[0], dot[1]);
    Bu.h[1] = pk(dot[2], dot[3]);
    Bu.h[2] = pk(dot[4], dot[5]);
    Bu.h[3] = pk(dot[6], dot[7]);
    const v8h A0 = *(const v8h*)(LW0 + ((p * 64 + q * 16 + n) << 2));
    f32x4 d1u = __builtin_amdgcn_mfma_f32_16x16x32_f16(A0, Bu.v, zc, 0, 0, 0);
    float g1[4];
#pragma unroll
    for (int r = 0; r < 4; ++r) {
      const float h1r = (float)H1.v[r];
      g1[r] = (1.f - h1r * h1r) * d1u[r];
    }
    U4 G1;
    G1.h[0] = pk(g1[0], g1[1]);
    G1.h[1] = pk(g1[2], g1[3]);
    v4h A1 = *(const v4h*)(LW1 + (p * 64 + a1off));
    A1 = act1 ? A1 : z4;
    f32x4 d2u = __builtin_amdgcn_mfma_f32_16x16x16f16(A1, G1.v, zc, 0, 0, 0);
    float g2[4];
#pragma unroll
    for (int r = 0; r < 4; ++r) {
      const float h2r = (float)H2.v[r];
      g2[r] = (1.f - h2r * h2r) * d2u[r];
    }
    U4 G2;
    G2.h[0] = pk(g2[0], g2[1]);
    G2.h[1] = pk(g2[2], g2[3]);
    // L3: t/s recompute (cached H2) + JVP, 8 independent MFMAs
#pragma unroll
    for (int b = 0; b < 4; ++b) {
      const bool act = (b < 2) == (q < 2);
      v4h Ab = *(const v4h*)(LW2 + (p * 256 + b * 64 + abbase));
      Ab = act ? Ab : z4;
      const f32x4 cb = *(const f32x4*)(LB2 + (p * 4 + b) * 16 + q * 4);
      f32x4 ob = __builtin_amdgcn_mfma_f32_16x16x16f16(Ab, H2.v, cb, 0, 0, 0);
      f32x4 jb = __builtin_amdgcn_mfma_f32_16x16x16f16(Ab, G2.v, zc, 0, 0, 0);
      float* dst = (b < 2) ? t8 : s8;
      float* jdst = (b < 2) ? ut8 : us8;
      const int off = (b & 1) * 4;
#pragma unroll
      for (int r = 0; r < 4; ++r) {
        dst[off + r] = ob[r];
        jdst[off + r] = jb[r];
      }
    }
    // invert coupling + dual update
#pragma unroll
    for (int j = 0; j < 8; ++j) {
      const float esi = __expf(-s8[j]);
      const float d = st[j] - t8[j];
      st[j] = d * esi;
      dme[j] = (dme[j] - ut8[j] - d * us8[j]) * esi;
    }
  }

  {
    float* oe = out + (size_t)e * 64;
    float4 v;
    v.x = av[0]; v.y = av[1]; v.z = av[2]; v.w = av[3];
    *(float4*)(oe + q * 8) = v;
    v.x = av[4]; v.y = av[5]; v.z = av[6]; v.w = av[7];
    *(float4*)(oe + q * 8 + 4) = v;
    v.x = bv[0]; v.y = bv[1]; v.z = bv[2]; v.w = bv[3];
    *(float4*)(oe + 32 + q * 8) = v;
    v.x = bv[4]; v.y = bv[5]; v.z = bv[6]; v.w = bv[7];
    *(float4*)(oe + 32 + q * 8 + 4) = v;
  }
}

extern "C" void kernel_launch(void* const* d_in, const int* in_sizes, int n_in,
                              void* d_out, int out_size, void* d_ws,
                              size_t ws_size, hipStream_t stream) {
  const float* x  = (const float*)d_in[0];
  const float* xs = (const float*)d_in[1];
  const float* W0 = (const float*)d_in[2];
  const float* b0 = (const float*)d_in[3];
  const float* W1 = (const float*)d_in[4];
  const float* b1 = (const float*)d_in[5];
  const float* W2 = (const float*)d_in[6];
  const float* b2 = (const float*)d_in[7];
  float* out = (float*)d_out;

  dim3 grid(NB / 64);  // 256 blocks, 64 elements each (16 per wave)
  dim3 block(256);
  nf_policy_kernel<<<grid, block, 0, stream>>>(x, xs, W0, b0, W1, b1, W2, b2,
                                               out);
}